// Round 7
// baseline (2316.291 us; speedup 1.0000x reference)
//
#include <hip/hip_runtime.h>

// LIF, Round 7 — two-phase: parallel MFMA GEMM (xs = spikes@W^T) per t-chunk
// into workspace, then parallel-in-(b,g) LIF scan. Kernel boundaries = sync.
//
// Inputs fp32: spikes [T,B,F] exact {0,1}, W [F,F]. Outputs fp32: z_last,v,i.
// Numerics: W = Whi+Wmd+Wlo (3x bf16, R3-proven, 30x margin); spikes exact
// in bf16 (truncation). xs stays fp32 end-to-end.
// Fallback: if ws_size < ~66.5 MB, launch the R6 fused kernel instead
// (branch depends only on the constant ws_size -> same work every call).

typedef __attribute__((ext_vector_type(8))) short short8;   // 8 x bf16
typedef __attribute__((ext_vector_type(4))) float floatx4;

#define T_STEPS 1024
#define B_DIM   256
#define F_DIM   512
#define BF      (B_DIM * F_DIM)
#define TC      128                   // t-chunk
#define NCHUNK  (T_STEPS / TC)        // 8
#define MT      128
#define NT      128
#define ROWP    72                    // padded LDS row, ushorts (144 B)

// ws layout (bytes)
#define W3_BYTES (3 * 8 * 512 * 64 * 2)        // 1,572,864 (unpadded planes)
#define VST_OFF  ((size_t)W3_BYTES)
#define IST_OFF  (VST_OFF + (size_t)BF * 4)
#define XS_OFF   (IST_OFF + (size_t)BF * 4)
#define WS_NEED  (XS_OFF + (size_t)TC * BF * 4)   // 69,730,304

static __device__ __forceinline__ unsigned short f2bf_rne(float f) {
    unsigned u = __float_as_uint(f);
    return (unsigned short)((u + 0x7FFFu + ((u >> 16) & 1u)) >> 16);
}
static __device__ __forceinline__ float bf2f(unsigned short h) {
    return __uint_as_float(((unsigned)h) << 16);
}

// ---------------------------------------------------------------- w3_prep
// W [512 g][512 k] fp32 -> 3 bf16 planes, K-chunk-major:
// w3[((p*8+ks)*512 + g)*64 + kk] = split_p(W[g][ks*64+kk])
__global__ void w3_prep(const float* __restrict__ W,
                        unsigned short* __restrict__ w3)
{
    const int g = blockIdx.x;        // 512
    const int j = threadIdx.x;       // 64
    for (int ks = 0; ks < 8; ++ks) {
        float w = W[g * 512 + ks * 64 + j];
        unsigned short h = f2bf_rne(w);
        float r1 = w - bf2f(h);
        unsigned short m = f2bf_rne(r1);
        float r2 = r1 - bf2f(m);
        unsigned short l = f2bf_rne(r2);
        w3[((size_t)(0 * 8 + ks) * 512 + g) * 64 + j] = h;
        w3[((size_t)(1 * 8 + ks) * 512 + g) * 64 + j] = m;
        w3[((size_t)(2 * 8 + ks) * 512 + g) * 64 + j] = l;
    }
}

// ---------------------------------------------------------------- xs_gemm
// C[m,g] = sum_f A[m,f]*W[g,f] for one t-chunk: M = TC*B = 32768, N=K=512.
// 1024 blocks (256 m-tiles x 4 n-tiles) x 256 thr (4 waves, 64x64 each).
// K-loop: 8 steps of BK=64, software-pipelined (loads for ks+1 in flight
// during MFMA of ks — R3-proven shape). LDS rows padded to 72 ushorts
// (row*144B -> 16B-granule = row*9 mod 8: 2-way bank alias = free).
__global__ __launch_bounds__(256, 2)
void xs_gemm(const float* __restrict__ A,          // spikes chunk [TC*B][512]
             const unsigned short* __restrict__ w3,
             float* __restrict__ xs)               // [TC*B][512]
{
    __shared__ unsigned short sA[MT * ROWP];       // 18432 B
    __shared__ unsigned short sB[3 * NT * ROWP];   // 55296 B

    const int tid  = threadIdx.x;
    const unsigned lane = tid & 63u;
    const int w    = tid >> 6;                 // 0..3
    const int mt   = blockIdx.x >> 2;
    const int nt   = blockIdx.x & 3;
    const int m0   = mt * MT;
    const int g0   = nt * NT;
    const int mh   = (w & 1) * 64;
    const int nh   = (w >> 1) * 64;
    const int mrow = lane & 15;
    const int kq   = lane >> 4;

    floatx4 acc[4][4];
    #pragma unroll
    for (int mi = 0; mi < 4; ++mi)
        #pragma unroll
        for (int ni = 0; ni < 4; ++ni)
            acc[mi][ni] = (floatx4){0.f, 0.f, 0.f, 0.f};

    // A-load role: 16 thr/row, 8 rows apart -> row = ar+16p, float4 col = af
    const int ar = tid >> 4;       // 0..15
    const int af = tid & 15;       // 0..15

    float4 aA[8];
    uint4  bB[12];

    auto loadA = [&](int ks) {
        #pragma unroll
        for (int p = 0; p < 8; ++p)
            aA[p] = *(const float4*)(A + (size_t)(m0 + ar + 16 * p) * 512
                                       + ks * 64 + af * 4);
    };
    auto loadB = [&](int ks) {
        #pragma unroll
        for (int s = 0; s < 12; ++s) {
            const int q  = tid + 256 * s;      // 0..3071
            const int p  = q >> 10;            // plane
            const int qq = q & 1023;
            const int gr = qq >> 3;            // 0..127
            const int ci = qq & 7;
            bB[s] = *(const uint4*)(w3 + ((size_t)(p * 8 + ks) * 512 + g0 + gr) * 64
                                       + ci * 8);
        }
    };
    auto writeA = [&]() {
        #pragma unroll
        for (int p = 0; p < 8; ++p) {
            unsigned u0 = __float_as_uint(aA[p].x);
            unsigned u1 = __float_as_uint(aA[p].y);
            unsigned u2 = __float_as_uint(aA[p].z);
            unsigned u3 = __float_as_uint(aA[p].w);
            uint2 d;   // spikes {0,1}: bf16 truncation exact
            d.x = (u0 >> 16) | (u1 & 0xFFFF0000u);
            d.y = (u2 >> 16) | (u3 & 0xFFFF0000u);
            *(uint2*)&sA[(ar + 16 * p) * ROWP + af * 4] = d;
        }
    };
    auto writeB = [&]() {
        #pragma unroll
        for (int s = 0; s < 12; ++s) {
            const int q  = tid + 256 * s;
            const int p  = q >> 10;
            const int qq = q & 1023;
            const int gr = qq >> 3;
            const int ci = qq & 7;
            *(uint4*)&sB[p * (NT * ROWP) + gr * ROWP + ci * 8] = bB[s];
        }
    };

    loadA(0); loadB(0);
    for (int ks = 0; ks < 8; ++ks) {
        writeA(); writeB();
        __syncthreads();                        // tile ks staged
        if (ks < 7) { loadA(ks + 1); loadB(ks + 1); }   // hide under MFMA

        #pragma unroll
        for (int kc = 0; kc < 2; ++kc) {
            short8 afr[4];
            #pragma unroll
            for (int mi = 0; mi < 4; ++mi)
                afr[mi] = *(const short8*)(sA + (mh + mi * 16 + mrow) * ROWP
                                              + kc * 32 + kq * 8);
            #pragma unroll
            for (int p = 0; p < 3; ++p) {
                short8 bfr[4];
                #pragma unroll
                for (int ni = 0; ni < 4; ++ni)
                    bfr[ni] = *(const short8*)(sB + p * (NT * ROWP)
                                                  + (nh + ni * 16 + mrow) * ROWP
                                                  + kc * 32 + kq * 8);
                #pragma unroll
                for (int mi = 0; mi < 4; ++mi)
                    #pragma unroll
                    for (int ni = 0; ni < 4; ++ni)
                        acc[mi][ni] = __builtin_amdgcn_mfma_f32_16x16x32_bf16(
                            afr[mi], bfr[ni], acc[mi][ni], 0, 0, 0);
            }
        }
        __syncthreads();                        // reads done before overwrite
    }

    // epilogue: C-layout col = lane&15 (g), row = kq*4+r (m)
    #pragma unroll
    for (int mi = 0; mi < 4; ++mi)
        #pragma unroll
        for (int ni = 0; ni < 4; ++ni) {
            const int gg = g0 + nh + ni * 16 + mrow;
            const int mm = m0 + mh + mi * 16 + kq * 4;
            #pragma unroll
            for (int r = 0; r < 4; ++r)
                xs[(size_t)(mm + r) * 512 + gg] = acc[mi][ni][r];
        }
}

// ---------------------------------------------------------------- lif_scan
// 131072 independent chains, TC steps each; 8-deep register prefetch.
__global__ __launch_bounds__(256)
void lif_scan(const float* __restrict__ xs, float* __restrict__ vst,
              float* __restrict__ ist, float* __restrict__ out,
              int first, int last)
{
    const int n = blockIdx.x * 256 + threadIdx.x;
    float v, cu;
    if (first) { v = 0.f; cu = 0.f; }
    else       { v = vst[n]; cu = ist[n]; }
    float zf = 0.f;

    float buf[8];
    #pragma unroll
    for (int j = 0; j < 8; ++j) buf[j] = xs[(size_t)j * BF + n];

    #pragma unroll 8
    for (int t = 0; t < TC; ++t) {
        float x    = buf[t & 7];
        float vdec = v + 0.1f * ((0.0f - v) + cu);   // DT*TAU_MEM_INV = 0.1
        float idec = cu - 0.2f * cu;                  // DT*TAU_SYN_INV = 0.2
        bool  spk  = (vdec - 1.0f) > 0.0f;            // heaviside
        zf = spk ? 1.0f : 0.0f;
        v  = spk ? 0.0f : vdec;                       // V_RESET = 0
        cu = idec + x;
        if (t + 8 < TC) buf[t & 7] = xs[(size_t)(t + 8) * BF + n];
    }

    vst[n] = v; ist[n] = cu;
    if (last) { out[n] = zf; out[BF + n] = v; out[2 * BF + n] = cu; }
}

// ========================================================== R6 fallback
#define GBLK 64
#define ROWS 8
#define ZIDX (512 * GBLK)
#define LCAP 128
#define WL_WORDS (513 * GBLK)

__global__ __launch_bounds__(512, 1)
void lif_sparse2(const float* __restrict__ spikes,
                 const float* __restrict__ W,
                 float* __restrict__ out)
{
    __shared__ float    Wl[WL_WORDS];
    __shared__ __align__(16) unsigned lists[ROWS * 4 * LCAP];

    const int tid  = threadIdx.x;
    const unsigned lane = tid & 63u;
    const int wav  = tid >> 6;
    const int bid  = blockIdx.x;
    const int bt   = bid & 31;
    const int gb   = bid >> 5;
    const int g0   = gb * GBLK;
    const int row  = bt * ROWS + wav;

    {
        const int gi = tid & 63;
        const int fc = tid >> 6;
        const float* wrow = W + (size_t)(g0 + gi) * F_DIM + fc * 64;
        #pragma unroll
        for (int u = 0; u < 16; ++u) {
            float4 wv = *(const float4*)(wrow + u * 4);
            const int f = fc * 64 + u * 4;
            Wl[(f + 0) * GBLK + gi] = wv.x;
            Wl[(f + 1) * GBLK + gi] = wv.y;
            Wl[(f + 2) * GBLK + gi] = wv.z;
            Wl[(f + 3) * GBLK + gi] = wv.w;
        }
        if (tid < GBLK) Wl[ZIDX + tid] = 0.f;
    }
    __syncthreads();

    unsigned* lb0 = lists + wav * (4 * LCAP);
    unsigned* lb1 = lb0 + LCAP;
    unsigned* lb2 = lb0 + 2 * LCAP;
    unsigned* lb3 = lb0 + 3 * LCAP;

    const size_t rowbase = (size_t)row * F_DIM + lane;
    const unsigned vbase = lane * GBLK;

    float spA[8], spB[8];
    auto loadspA = [&](int t) {
        const float* p = spikes + (size_t)t * BF + rowbase;
        #pragma unroll
        for (int j = 0; j < 8; ++j) spA[j] = p[j * 64];
    };
    auto loadspB = [&](int t) {
        const float* p = spikes + (size_t)t * BF + rowbase;
        #pragma unroll
        for (int j = 0; j < 8; ++j) spB[j] = p[j * 64];
    };

    auto decode = [&](unsigned* lb, const float* sp) -> int {
        int cnt = 0;
        #pragma unroll
        for (int j = 0; j < 8; ++j) {
            bool act = (__float_as_uint(sp[j]) != 0u);
            unsigned long long m = __ballot(act);
            unsigned rank = __builtin_amdgcn_mbcnt_hi(
                (unsigned)(m >> 32), __builtin_amdgcn_mbcnt_lo((unsigned)m, 0u));
            if (act) lb[cnt + rank] = (unsigned)(j * (64 * GBLK)) + vbase;
            cnt += (int)__popcll(m);
        }
        return cnt;
    };

    auto pad2 = [&](unsigned* la, int ca, unsigned* lb, int cb) -> int {
        int m = (ca > cb) ? ca : cb;
        if (m < 4) m = 4;
        const int mc = (m + 3) & ~3;
        const int pa = mc - ca;
        if ((int)lane < pa)       la[ca + lane]      = ZIDX;
        if ((int)lane + 64 < pa)  la[ca + 64 + lane] = ZIDX;
        const int pb = mc - cb;
        if ((int)lane < pb)       lb[cb + lane]      = ZIDX;
        if ((int)lane + 64 < pb)  lb[cb + 64 + lane] = ZIDX;
        return mc >> 2;
    };

    struct WV { float a[4]; float b[4]; };
    auto ldw = [&](WV& wv, uint4 cA, uint4 cB) {
        wv.a[0] = Wl[cA.x + lane]; wv.a[1] = Wl[cA.y + lane];
        wv.a[2] = Wl[cA.z + lane]; wv.a[3] = Wl[cA.w + lane];
        wv.b[0] = Wl[cB.x + lane]; wv.b[1] = Wl[cB.y + lane];
        wv.b[2] = Wl[cB.z + lane]; wv.b[3] = Wl[cB.w + lane];
    };

    auto consume2 = [&](const unsigned* la, const unsigned* lb, int nch) -> float2 {
        const uint4* chA = (const uint4*)la;
        const uint4* chB = (const uint4*)lb;
        float aA0 = 0.f, aA1 = 0.f, aA2 = 0.f, aA3 = 0.f;
        float aB0 = 0.f, aB1 = 0.f, aB2 = 0.f, aB3 = 0.f;
        auto accf = [&](const WV& wv) {
            aA0 += wv.a[0]; aA1 += wv.a[1]; aA2 += wv.a[2]; aA3 += wv.a[3];
            aB0 += wv.b[0]; aB1 += wv.b[1]; aB2 += wv.b[2]; aB3 += wv.b[3];
        };
        WV w0, w1;
        uint4 cNA = chA[0], cNB = chB[0];
        ldw(w0, cNA, cNB);
        cNA = chA[1]; cNB = chB[1];
        int i = 1;
        for (; i + 1 < nch; i += 2) {
            ldw(w1, cNA, cNB);
            cNA = chA[i + 1]; cNB = chB[i + 1];
            accf(w0);
            ldw(w0, cNA, cNB);
            cNA = chA[i + 2]; cNB = chB[i + 2];
            accf(w1);
        }
        if (i < nch) { ldw(w1, cNA, cNB); accf(w0); accf(w1); }
        else         { accf(w0); }
        return make_float2((aA0 + aA1) + (aA2 + aA3), (aB0 + aB1) + (aB2 + aB3));
    };

    float v = 0.f, cu = 0.f, zf = 0.f;
    auto lif = [&](float x) {
        float vdec = v + 0.1f * ((0.0f - v) + cu);
        float idec = cu - 0.2f * cu;
        bool  spk  = (vdec - 1.0f) > 0.0f;
        zf = spk ? 1.0f : 0.0f;
        v  = spk ? 0.0f : vdec;
        cu = idec + x;
    };

    loadspA(0); loadspB(1);
    int c0 = decode(lb0, spA);
    int c1 = decode(lb1, spB);
    int nCur = pad2(lb0, c0, lb1, c1);
    loadspA(2); loadspB(3);

    for (int t = 0; t < T_STEPS; t += 2) {
        int d0 = decode(lb2, spA);
        int d1 = decode(lb3, spB);
        int nNext = pad2(lb2, d0, lb3, d1);
        int ta = t + 4, tb = t + 5;
        loadspA(ta < T_STEPS ? ta : T_STEPS - 1);
        loadspB(tb < T_STEPS ? tb : T_STEPS - 1);

        float2 x = consume2(lb0, lb1, nCur);
        lif(x.x);
        lif(x.y);

        unsigned* s;
        s = lb0; lb0 = lb2; lb2 = s;
        s = lb1; lb1 = lb3; lb3 = s;
        nCur = nNext;
    }

    const size_t oidx = (size_t)row * F_DIM + g0 + lane;
    out[oidx]          = zf;
    out[BF + oidx]     = v;
    out[2 * BF + oidx] = cu;
}

// ========================================================== launch
extern "C" void kernel_launch(void* const* d_in, const int* in_sizes, int n_in,
                              void* d_out, int out_size, void* d_ws, size_t ws_size,
                              hipStream_t stream)
{
    const float* spikes = (const float*)d_in[0];   // [T,B,F] fp32
    const float* W      = (const float*)d_in[1];   // [F,F]   fp32
    float* out          = (float*)d_out;           // [3,B,F] fp32

    if (ws_size >= WS_NEED) {
        unsigned short* w3 = (unsigned short*)d_ws;
        float* vst = (float*)((char*)d_ws + VST_OFF);
        float* ist = (float*)((char*)d_ws + IST_OFF);
        float* xs  = (float*)((char*)d_ws + XS_OFF);

        w3_prep<<<dim3(512), dim3(64), 0, stream>>>(W, w3);
        for (int c = 0; c < NCHUNK; ++c) {
            xs_gemm<<<dim3(1024), dim3(256), 0, stream>>>(
                spikes + (size_t)c * TC * BF, w3, xs);
            lif_scan<<<dim3(512), dim3(256), 0, stream>>>(
                xs, vst, ist, out, c == 0 ? 1 : 0, c == NCHUNK - 1 ? 1 : 0);
        }
    } else {
        lif_sparse2<<<dim3(256), dim3(512), 0, stream>>>(spikes, W, out);
    }
}